// Round 9
// baseline (117.295 us; speedup 1.0000x reference)
//
#include <hip/hip_runtime.h>
#include <math.h>

#define Bn 64
#define Cn 64
#define Sn 128
#define Hn 512
#define Dn 65536
#define SSn 16384

using f32x4 = __attribute__((ext_vector_type(4))) float;
using bf16x8 = __attribute__((ext_vector_type(8))) short;

__device__ __forceinline__ float wredf(float v) {
#pragma unroll
    for (int o = 32; o > 0; o >>= 1) v += __shfl_down(v, o, 64);
    return v;
}

__device__ __forceinline__ unsigned short f2bf(float f) {
    unsigned int u = __float_as_uint(f);
    u += 0x7fffu + ((u >> 16) & 1u);
    return (unsigned short)(u >> 16);
}
__device__ __forceinline__ float bf2f(unsigned short h) {
    return __uint_as_float(((unsigned int)h) << 16);
}

// ===== Kernel A: gram (bid<128) | dist-dots + w-copy (bid 128..255) ========
// 256 blocks x 512 thr = exactly 1 block/CU.
// Gram: 1 block/mat, 8 waves as 4 row-groups x 2 col-groups (24 ds_read_b128
// per chunk per wave vs 36 for 1D split), bf16 3-split MFMA, fp32 G stored in
// a lane-contiguous PERMUTED layout (dots over G are permutation-invariant).
// Dist-dots: bf16-hi MFMA on K-slice 512; stages w anyway, so it also writes
// the centroid copy for its slice (saves a separate 16MB read).
__global__ __launch_bounds__(512) void kA(const float* __restrict__ x,
                                          const float* __restrict__ w,
                                          float* __restrict__ gF,
                                          float* __restrict__ rsT,
                                          float* __restrict__ hpartG,
                                          float* __restrict__ x2,
                                          float* __restrict__ w2,
                                          float* __restrict__ partials,
                                          float* __restrict__ outcpy) {
    __shared__ __align__(16) unsigned char smem[67584];
    const int bid = blockIdx.x;
    const int tid = threadIdx.x;
    const int lane = tid & 63;
    const int wv = tid >> 6;            // 0..7
    const int lrow = lane & 15;
    const int lk8 = (lane >> 4) * 8;
    const int crow4 = (lane >> 4) * 4;
    if (bid < 128) {  // ---- gram: full 128x128 output, mat = bid ----
        __shared__ float sA[8], sB[8];
        const int mat = bid;
        const int wm = wv >> 1;         // 0..3: rows wm*32 .. +32
        const int wc = wv & 1;          // 0..1: cols wc*64 .. +64
        const float* src = (mat < Bn) ? (x + (size_t)mat * Dn) : (w + (size_t)(mat - Bn) * Dn);
        unsigned short (*hi)[72] = (unsigned short(*)[72])smem;
        unsigned short (*lo)[72] = (unsigned short(*)[72])(smem + 18432);
        f32x4 acc[2][4] = {};
        float ssq = 0.f;
        float4 cur[4], nxt[4];
#pragma unroll
        for (int p = 0; p < 4; ++p) {
            const int f = tid + 512 * p;            // 0..2047
            cur[p] = *(const float4*)(src + (size_t)(f >> 4) * Hn + (f & 15) * 4);
        }
        for (int c = 0; c < 8; ++c) {
#pragma unroll
            for (int p = 0; p < 4; ++p) {
                const int f = tid + 512 * p;
                const int r = f >> 4, c4 = (f & 15) * 4;
                float4 v = cur[p];
                ssq += v.x * v.x + v.y * v.y + v.z * v.z + v.w * v.w;
                unsigned short h0 = f2bf(v.x), h1 = f2bf(v.y), h2 = f2bf(v.z), h3 = f2bf(v.w);
                *(ushort4*)&hi[r][c4] = make_ushort4(h0, h1, h2, h3);
                *(ushort4*)&lo[r][c4] = make_ushort4(f2bf(v.x - bf2f(h0)), f2bf(v.y - bf2f(h1)),
                                                     f2bf(v.z - bf2f(h2)), f2bf(v.w - bf2f(h3)));
            }
            if (c < 7) {
#pragma unroll
                for (int p = 0; p < 4; ++p) {
                    const int f = tid + 512 * p;
                    nxt[p] = *(const float4*)(src + (size_t)(f >> 4) * Hn + (c + 1) * 64 + (f & 15) * 4);
                }
            }
            __syncthreads();
#pragma unroll
            for (int ks = 0; ks < 64; ks += 32) {
                bf16x8 ah[2], al[2];
#pragma unroll
                for (int i = 0; i < 2; ++i) {
                    const int arow = wm * 32 + i * 16 + lrow;
                    ah[i] = *(const bf16x8*)&hi[arow][ks + lk8];
                    al[i] = *(const bf16x8*)&lo[arow][ks + lk8];
                }
#pragma unroll
                for (int j = 0; j < 4; ++j) {
                    const int brow = wc * 64 + j * 16 + lrow;
                    bf16x8 bh = *(const bf16x8*)&hi[brow][ks + lk8];
                    bf16x8 bl = *(const bf16x8*)&lo[brow][ks + lk8];
#pragma unroll
                    for (int i = 0; i < 2; ++i) {
                        acc[i][j] = __builtin_amdgcn_mfma_f32_16x16x32_bf16(ah[i], bh, acc[i][j], 0, 0, 0);
                        acc[i][j] = __builtin_amdgcn_mfma_f32_16x16x32_bf16(ah[i], bl, acc[i][j], 0, 0, 0);
                        acc[i][j] = __builtin_amdgcn_mfma_f32_16x16x32_bf16(al[i], bh, acc[i][j], 0, 0, 0);
                    }
                }
            }
            __syncthreads();
            if (c < 7) {
#pragma unroll
                for (int p = 0; p < 4; ++p) cur[p] = nxt[p];
            }
        }
        // store fp32 G, permuted coalesced: pos = wv*2048 + (i*4+j)*256 + lane*4 + r
        float* dst = gF + (size_t)mat * SSn + wv * 2048;
        float sq = 0.f;
#pragma unroll
        for (int i = 0; i < 2; ++i)
#pragma unroll
            for (int j = 0; j < 4; ++j) {
                f32x4 v = acc[i][j];
                sq += v[0] * v[0] + v[1] * v[1] + v[2] * v[2] + v[3] * v[3];
                *(f32x4*)(dst + (i * 4 + j) * 256 + lane * 4) = v;
            }
        // row sums: per-wave 64-col partials, combine halves through LDS
        float* sRS = (float*)smem;  // [128][2], hi/lo dead after final sync
#pragma unroll
        for (int i = 0; i < 2; ++i)
#pragma unroll
            for (int r = 0; r < 4; ++r) {
                float rs = acc[i][0][r] + acc[i][1][r] + acc[i][2][r] + acc[i][3][r];
                rs += __shfl_xor(rs, 1, 64);
                rs += __shfl_xor(rs, 2, 64);
                rs += __shfl_xor(rs, 4, 64);
                rs += __shfl_xor(rs, 8, 64);
                if (lrow == 0) sRS[(wm * 32 + i * 16 + crow4 + r) * 2 + wc] = rs;
            }
        sq = wredf(sq);
        ssq = wredf(ssq);
        if (lane == 0) { sA[wv] = sq; sB[wv] = ssq; }
        __syncthreads();
        if (tid < 128) rsT[(size_t)tid * 128 + mat] = sRS[tid * 2] + sRS[tid * 2 + 1];
        if (tid == 0) {
            float g2 = 0.f, tr = 0.f;
#pragma unroll
            for (int i = 0; i < 8; ++i) { g2 += sA[i]; tr += sB[i]; }
            hpartG[mat] = g2;
            if (mat < Bn) x2[mat] = tr; else w2[mat - Bn] = tr;
        }
    } else {  // ---- dist dots (bf16-hi MFMA, K=512) + centroid copy ----
        const int did = bid - 128;  // 0..127
        unsigned short (*la)[264] = (unsigned short(*)[264])smem;
        unsigned short (*lb)[264] = (unsigned short(*)[264])(smem + 33792);
        const int rg = wv >> 1, cgb = (wv & 1) * 2;
        f32x4 acc[2] = {};
        for (int cc = 0; cc < 2; ++cc) {
            const int k0 = did * 512 + cc * 256;
            __syncthreads();
#pragma unroll
            for (int p = 0; p < 8; ++p) {
                const int f = tid + 512 * p;   // 0..4095 = 64 rows x 64 f4
                const int row = f >> 6, c4 = (f & 63) * 4;
                float4 vx = *(const float4*)(x + (size_t)row * Dn + k0 + c4);
                float4 vw = *(const float4*)(w + (size_t)row * Dn + k0 + c4);
                *(ushort4*)&la[row][c4] = make_ushort4(f2bf(vx.x), f2bf(vx.y), f2bf(vx.z), f2bf(vx.w));
                *(ushort4*)&lb[row][c4] = make_ushort4(f2bf(vw.x), f2bf(vw.y), f2bf(vw.z), f2bf(vw.w));
                float* dc = outcpy + (size_t)row * Dn + k0 + c4;  // 4B-aligned dst
                dc[0] = vw.x; dc[1] = vw.y; dc[2] = vw.z; dc[3] = vw.w;
            }
            __syncthreads();
#pragma unroll
            for (int ks = 0; ks < 8; ++ks) {
                bf16x8 a = *(const bf16x8*)&la[rg * 16 + lrow][ks * 32 + lk8];
#pragma unroll
                for (int q = 0; q < 2; ++q) {
                    bf16x8 b = *(const bf16x8*)&lb[(cgb + q) * 16 + lrow][ks * 32 + lk8];
                    acc[q] = __builtin_amdgcn_mfma_f32_16x16x32_bf16(a, b, acc[q], 0, 0, 0);
                }
            }
        }
        float* p = partials + (size_t)did * 4096;
#pragma unroll
        for (int q = 0; q < 2; ++q)
#pragma unroll
            for (int r = 0; r < 4; ++r)
                p[(rg * 16 + crow4 + r) * 64 + (cgb + q) * 16 + lrow] = acc[q][r];
    }
}

// ===== Kernel B: hxy-dots K=256 (bid<64) | dist-reduce (64..127) | sumS (128)
__global__ __launch_bounds__(256) void kB(const float* __restrict__ gF,
                                          const float* __restrict__ partials,
                                          const float* __restrict__ rsT,
                                          const float* __restrict__ hpartG,
                                          const float* __restrict__ x2,
                                          const float* __restrict__ w2,
                                          float* __restrict__ partials2,
                                          float* __restrict__ Sv,
                                          float* __restrict__ hxx,
                                          float* __restrict__ hyy,
                                          float* __restrict__ od) {
    __shared__ __align__(16) unsigned char smem[65536];
    const int bid = blockIdx.x;
    const int tid = threadIdx.x;
    if (bid < 64) {  // ---- fp32 dots over permuted G, K=256 in 4 chunks ----
        float (*la)[68] = (float(*)[68])smem;
        float (*lb)[68] = (float(*)[68])(smem + 17408);
        const int slc = (tid & 15) * 4;
        const int ry = tid >> 4, tx = tid & 15;
        float acc[4][4] = {};
        for (int c = 0; c < 4; ++c) {
            const int k0 = bid * 256 + c * 64;
            __syncthreads();
            for (int r = tid >> 4; r < 64; r += 16) {
                *(float4*)&la[r][slc] = *(const float4*)(gF + (size_t)r * SSn + k0 + slc);
                *(float4*)&lb[r][slc] = *(const float4*)(gF + (size_t)(64 + r) * SSn + k0 + slc);
            }
            __syncthreads();
            for (int k = 0; k < 64; k += 4) {
                float4 av[4], bv[4];
#pragma unroll
                for (int i = 0; i < 4; ++i) av[i] = *(const float4*)&la[4 * ry + i][k];
#pragma unroll
                for (int j = 0; j < 4; ++j) bv[j] = *(const float4*)&lb[16 * j + tx][k];
#pragma unroll
                for (int i = 0; i < 4; ++i)
#pragma unroll
                    for (int j = 0; j < 4; ++j)
                        acc[i][j] += av[i].x * bv[j].x + av[i].y * bv[j].y +
                                     av[i].z * bv[j].z + av[i].w * bv[j].w;
            }
        }
        float* p = partials2 + (size_t)bid * 4096;
#pragma unroll
        for (int i = 0; i < 4; ++i)
#pragma unroll
            for (int j = 0; j < 4; ++j)
                p[(4 * ry + i) * 64 + 16 * j + tx] = acc[i][j];
    } else if (bid < 128) {  // ---- dist reduce (P=128) ----
        double* red = (double*)smem;
        const int b2 = bid - 64;
        const int o = tid & 63, sl = tid >> 6;
        const int i = b2 * 64 + o;
        double s = 0;
        for (int t = 0; t < 32; ++t)
            s += (double)partials[(size_t)(sl + 4 * t) * 4096 + i];
        red[sl * 64 + o] = s;
        __syncthreads();
        if (tid < 64) {
            double t = red[tid] + red[64 + tid] + red[128 + tid] + red[192 + tid];
            float d2 = x2[b2] + w2[tid] - 2.f * (float)t;
            od[b2 * 64 + tid] = sqrtf(fmaxf(d2, 0.f));
        }
    } else {  // ---- sumS: LDS-staged rsT; S, hxx, hyy ----
        float* rl = (float*)smem;  // 128*128 floats = 64KB
        for (int p = 0; p < 16; ++p) {
            const int f4 = tid + 256 * p;
            *(float4*)(rl + 4 * f4) = *(const float4*)(rsT + 4 * f4);
        }
        __syncthreads();
        if (tid < 128) {
            float s = 0.f, q = 0.f;
            for (int t = 0; t < 128; ++t) {
                float v = rl[t * 128 + tid];
                s += v; q += v * v;
            }
            Sv[tid] = s;
            double val = (double)hpartG[tid] - (double)q * (1.0 / 64.0)
                       + (double)s * (double)s * (1.0 / 16384.0);
            if (tid < 64) hxx[tid] = (float)val; else hyy[tid - 64] = (float)val;
        }
    }
}

// ===== Kernel C: hxy reduce (P=64) + centering corrections (64 x 256) ======
__global__ __launch_bounds__(256) void kC(const float* __restrict__ partials2,
                                          const float* __restrict__ rsT,
                                          const float* __restrict__ Sv,
                                          double* __restrict__ hxy) {
    __shared__ double red[256];
    const int b = blockIdx.x;
    const int o = threadIdx.x & 63;
    const int sl = threadIdx.x >> 6;
    const int i = b * 64 + o;
    double s = 0;
    for (int t = 0; t < 16; ++t)
        s += (double)partials2[(size_t)(sl + 4 * t) * 4096 + i];
    double corr = 0;
    for (int t = 0; t < 32; ++t) {
        const int ss = sl * 32 + t;
        corr += (double)rsT[ss * 128 + b] * (double)rsT[ss * 128 + 64 + o];
    }
    red[sl * 64 + o] = s - corr * (1.0 / 64.0);
    __syncthreads();
    if (threadIdx.x < 64) {
        double t = red[threadIdx.x] + red[64 + threadIdx.x] +
                   red[128 + threadIdx.x] + red[192 + threadIdx.x];
        t += (double)Sv[b] * (double)Sv[64 + threadIdx.x] * (1.0 / 16384.0);
        hxy[b * 64 + threadIdx.x] = t;
    }
}

// ===== Kernel D: parallel argmin (== argmax of -log(r+eps), first-wins) ====
__global__ void finalize_k(const double* __restrict__ hxy, const float* __restrict__ hxx,
                           const float* __restrict__ hyy, float* __restrict__ out0,
                           float* __restrict__ oidx) {
    __shared__ double inv_sx[64], inv_sy[64];
    __shared__ double qv[256];
    __shared__ int qi[256];
    __shared__ int sidx[64];
    __shared__ double sred[4];
    const int tid = threadIdx.x;  // 256
    if (tid < 64) {
        inv_sx[tid] = 1.0 / sqrt((double)hxx[tid]);
        inv_sy[tid] = 1.0 / sqrt((double)hyy[tid]);
    }
    __syncthreads();
    {   // 4 threads per row b, 16 candidates each
        const int b = tid >> 2, q = tid & 3;
        double best = 1e300; int bi = 64;
        for (int c = q * 16; c < q * 16 + 16; ++c) {
            double v = fabs(hxy[b * 64 + c]) * inv_sy[c];
            if (v < best) { best = v; bi = c; }
        }
        qv[tid] = best; qi[tid] = bi;
    }
    __syncthreads();
    if (tid < 64) {
        double best = qv[4 * tid]; int bi = qi[4 * tid];
        for (int q = 1; q < 4; ++q) {
            if (qv[4 * tid + q] < best) { best = qv[4 * tid + q]; bi = qi[4 * tid + q]; }
        }
        sidx[tid] = bi;
        oidx[tid] = (float)bi;
    }
    __syncthreads();
    double s = 0.0;
    for (int e = tid; e < 4096; e += 256) {
        const int b = e >> 6, c = e & 63;
        const int ic = sidx[c];
        s += fabs(hxy[b * 64 + ic]) * inv_sx[b] * inv_sy[ic];
    }
#pragma unroll
    for (int o = 32; o > 0; o >>= 1) s += __shfl_down(s, o, 64);
    if ((tid & 63) == 0) sred[tid >> 6] = s;
    __syncthreads();
    if (tid == 0) {
        double t = sred[0] + sred[1] + sred[2] + sred[3];
        out0[0] = (float)(-log(t / 4096.0 + 1e-8));
    }
}

extern "C" void kernel_launch(void* const* d_in, const int* in_sizes, int n_in,
                              void* d_out, int out_size, void* d_ws, size_t ws_size,
                              hipStream_t stream) {
    const float* x = (const float*)d_in[0];   // (64, 65536)
    const float* w = (const float*)d_in[1];   // (64, 65536)
    float* out = (float*)d_out;
    // out: [0]=loss, [1..4096]=dist, [4097..4198400]=centroid copy, [4198401..]=idx
    float* ws = (float*)d_ws;
    float* gF        = ws;                        // 128*16384 fp32 (permuted grams)
    float* partials  = ws + 2097152;              // 128*4096 (dist)
    float* partials2 = ws + 2621440;              // 64*4096 (hxy)
    float* rsT       = ws + 2883584;              // 128*128 [s][mat]
    float* hpartG    = ws + 2899968;              // 128
    float* Sv        = ws + 2900096;              // 128
    float* x2        = ws + 2900224;              // 64
    float* w2        = ws + 2900288;              // 64
    float* hxx       = ws + 2900352;              // 64
    float* hyy       = ws + 2900416;              // 64
    double* hxyD     = (double*)(ws + 2900480);   // 4096 doubles (8B aligned)

    kA<<<256, 512, 0, stream>>>(x, w, gF, rsT, hpartG, x2, w2, partials, out + 4097);
    kB<<<129, 256, 0, stream>>>(gF, partials, rsT, hpartG, x2, w2,
                                partials2, Sv, hxx, hyy, out + 1);
    kC<<<64, 256, 0, stream>>>(partials2, rsT, Sv, hxyD);
    finalize_k<<<1, 256, 0, stream>>>(hxyD, hxx, hyy, out, out + 4198401);
}

// Round 10
// 116.947 us; speedup vs baseline: 1.0030x; 1.0030x over previous
//
#include <hip/hip_runtime.h>
#include <hip/hip_bf16.h>
#include <math.h>

#define Bn 64
#define Cn 64
#define Sn 128
#define Hn 512
#define Dn 65536
#define SSn 16384

using f32x4 = __attribute__((ext_vector_type(4))) float;
using bf16x8 = __attribute__((ext_vector_type(8))) short;

__device__ __forceinline__ float wredf(float v) {
#pragma unroll
    for (int o = 32; o > 0; o >>= 1) v += __shfl_down(v, o, 64);
    return v;
}

// fp32 -> bf16 (RNE) via HIP cast; compiler fuses pairs into v_cvt_pk_bf16_f32
__device__ __forceinline__ unsigned short f2bf(float f) {
    __hip_bfloat16 h = __float2bfloat16(f);
    unsigned short u;
    __builtin_memcpy(&u, &h, 2);
    return u;
}
__device__ __forceinline__ void split2(float f, unsigned short& hi, unsigned short& lo) {
    __hip_bfloat16 h = __float2bfloat16(f);
    float rem = f - __bfloat162float(h);
    __hip_bfloat16 l = __float2bfloat16(rem);
    __builtin_memcpy(&hi, &h, 2);
    __builtin_memcpy(&lo, &l, 2);
}

// ===== Kernel A: gram (bid<128) | dist-dots + w-copy (bid 128..255) ========
// 256 blocks x 512 thr; static LDS 36.9KB -> multiple blocks/CU co-resident.
// Gram: 1 block/mat, 8 waves as 4 row-groups x 2 col-groups, bf16 3-split
// MFMA, fp32 G stored in a lane-contiguous PERMUTED layout (dots over G are
// permutation-invariant). Dist-dots: bf16-hi MFMA on K=512 in 128-col
// chunks; also writes its staged w slice as the centroid copy.
__global__ __launch_bounds__(512) void kA(const float* __restrict__ x,
                                          const float* __restrict__ w,
                                          float* __restrict__ gF,
                                          float* __restrict__ rsT,
                                          float* __restrict__ hpartG,
                                          float* __restrict__ x2,
                                          float* __restrict__ w2,
                                          float* __restrict__ partials,
                                          float* __restrict__ outcpy) {
    __shared__ __align__(16) unsigned char smem[36864];
    const int bid = blockIdx.x;
    const int tid = threadIdx.x;
    const int lane = tid & 63;
    const int wv = tid >> 6;            // 0..7
    const int lrow = lane & 15;
    const int lk8 = (lane >> 4) * 8;
    const int crow4 = (lane >> 4) * 4;
    if (bid < 128) {  // ---- gram: full 128x128 output, mat = bid ----
        __shared__ float sA[8], sB[8];
        const int mat = bid;
        const int wm = wv >> 1;         // 0..3: rows wm*32 .. +32
        const int wc = wv & 1;          // 0..1: cols wc*64 .. +64
        const float* src = (mat < Bn) ? (x + (size_t)mat * Dn) : (w + (size_t)(mat - Bn) * Dn);
        unsigned short (*hi)[72] = (unsigned short(*)[72])smem;
        unsigned short (*lo)[72] = (unsigned short(*)[72])(smem + 18432);
        f32x4 acc[2][4] = {};
        float ssq = 0.f;
        float4 cur[4], nxt[4];
#pragma unroll
        for (int p = 0; p < 4; ++p) {
            const int f = tid + 512 * p;            // 0..2047
            cur[p] = *(const float4*)(src + (size_t)(f >> 4) * Hn + (f & 15) * 4);
        }
        for (int c = 0; c < 8; ++c) {
#pragma unroll
            for (int p = 0; p < 4; ++p) {
                const int f = tid + 512 * p;
                const int r = f >> 4, c4 = (f & 15) * 4;
                float4 v = cur[p];
                ssq += v.x * v.x + v.y * v.y + v.z * v.z + v.w * v.w;
                ushort4 vh, vl;
                split2(v.x, vh.x, vl.x); split2(v.y, vh.y, vl.y);
                split2(v.z, vh.z, vl.z); split2(v.w, vh.w, vl.w);
                *(ushort4*)&hi[r][c4] = vh;
                *(ushort4*)&lo[r][c4] = vl;
            }
            if (c < 7) {
#pragma unroll
                for (int p = 0; p < 4; ++p) {
                    const int f = tid + 512 * p;
                    nxt[p] = *(const float4*)(src + (size_t)(f >> 4) * Hn + (c + 1) * 64 + (f & 15) * 4);
                }
            }
            __syncthreads();
#pragma unroll
            for (int ks = 0; ks < 64; ks += 32) {
                bf16x8 ah[2], al[2];
#pragma unroll
                for (int i = 0; i < 2; ++i) {
                    const int arow = wm * 32 + i * 16 + lrow;
                    ah[i] = *(const bf16x8*)&hi[arow][ks + lk8];
                    al[i] = *(const bf16x8*)&lo[arow][ks + lk8];
                }
#pragma unroll
                for (int j = 0; j < 4; ++j) {
                    const int brow = wc * 64 + j * 16 + lrow;
                    bf16x8 bh = *(const bf16x8*)&hi[brow][ks + lk8];
                    bf16x8 bl = *(const bf16x8*)&lo[brow][ks + lk8];
#pragma unroll
                    for (int i = 0; i < 2; ++i) {
                        acc[i][j] = __builtin_amdgcn_mfma_f32_16x16x32_bf16(ah[i], bh, acc[i][j], 0, 0, 0);
                        acc[i][j] = __builtin_amdgcn_mfma_f32_16x16x32_bf16(ah[i], bl, acc[i][j], 0, 0, 0);
                        acc[i][j] = __builtin_amdgcn_mfma_f32_16x16x32_bf16(al[i], bh, acc[i][j], 0, 0, 0);
                    }
                }
            }
            __syncthreads();
            if (c < 7) {
#pragma unroll
                for (int p = 0; p < 4; ++p) cur[p] = nxt[p];
            }
        }
        // store fp32 G, permuted coalesced: pos = wv*2048 + (i*4+j)*256 + lane*4 + r
        float* dst = gF + (size_t)mat * SSn + wv * 2048;
        float sq = 0.f;
#pragma unroll
        for (int i = 0; i < 2; ++i)
#pragma unroll
            for (int j = 0; j < 4; ++j) {
                f32x4 v = acc[i][j];
                sq += v[0] * v[0] + v[1] * v[1] + v[2] * v[2] + v[3] * v[3];
                *(f32x4*)(dst + (i * 4 + j) * 256 + lane * 4) = v;
            }
        // row sums: per-wave 64-col partials, combine halves through LDS
        float* sRS = (float*)smem;  // hi/lo dead after final sync
#pragma unroll
        for (int i = 0; i < 2; ++i)
#pragma unroll
            for (int r = 0; r < 4; ++r) {
                float rs = acc[i][0][r] + acc[i][1][r] + acc[i][2][r] + acc[i][3][r];
                rs += __shfl_xor(rs, 1, 64);
                rs += __shfl_xor(rs, 2, 64);
                rs += __shfl_xor(rs, 4, 64);
                rs += __shfl_xor(rs, 8, 64);
                if (lrow == 0) sRS[(wm * 32 + i * 16 + crow4 + r) * 2 + wc] = rs;
            }
        sq = wredf(sq);
        ssq = wredf(ssq);
        if (lane == 0) { sA[wv] = sq; sB[wv] = ssq; }
        __syncthreads();
        if (tid < 128) rsT[(size_t)tid * 128 + mat] = sRS[tid * 2] + sRS[tid * 2 + 1];
        if (tid == 0) {
            float g2 = 0.f, tr = 0.f;
#pragma unroll
            for (int i = 0; i < 8; ++i) { g2 += sA[i]; tr += sB[i]; }
            hpartG[mat] = g2;
            if (mat < Bn) x2[mat] = tr; else w2[mat - Bn] = tr;
        }
    } else {  // ---- dist dots (bf16-hi MFMA, K=512 in 4x128 chunks) + copy ----
        const int did = bid - 128;  // 0..127
        unsigned short (*la)[136] = (unsigned short(*)[136])smem;
        unsigned short (*lb)[136] = (unsigned short(*)[136])(smem + 17408);
        const int rg = wv >> 1, cgb = (wv & 1) * 2;
        f32x4 acc[2] = {};
        for (int cc = 0; cc < 4; ++cc) {
            const int k0 = did * 512 + cc * 128;
            __syncthreads();
#pragma unroll
            for (int p = 0; p < 4; ++p) {
                const int f = tid + 512 * p;   // 0..2047 = 64 rows x 32 f4
                const int row = f >> 5, c4 = (f & 31) * 4;
                float4 vx = *(const float4*)(x + (size_t)row * Dn + k0 + c4);
                float4 vw = *(const float4*)(w + (size_t)row * Dn + k0 + c4);
                *(ushort4*)&la[row][c4] = make_ushort4(f2bf(vx.x), f2bf(vx.y), f2bf(vx.z), f2bf(vx.w));
                *(ushort4*)&lb[row][c4] = make_ushort4(f2bf(vw.x), f2bf(vw.y), f2bf(vw.z), f2bf(vw.w));
                float* dc = outcpy + (size_t)row * Dn + k0 + c4;  // 4B-aligned dst
                dc[0] = vw.x; dc[1] = vw.y; dc[2] = vw.z; dc[3] = vw.w;
            }
            __syncthreads();
#pragma unroll
            for (int ks = 0; ks < 4; ++ks) {
                bf16x8 a = *(const bf16x8*)&la[rg * 16 + lrow][ks * 32 + lk8];
#pragma unroll
                for (int q = 0; q < 2; ++q) {
                    bf16x8 b = *(const bf16x8*)&lb[(cgb + q) * 16 + lrow][ks * 32 + lk8];
                    acc[q] = __builtin_amdgcn_mfma_f32_16x16x32_bf16(a, b, acc[q], 0, 0, 0);
                }
            }
        }
        float* p = partials + (size_t)did * 4096;
#pragma unroll
        for (int q = 0; q < 2; ++q)
#pragma unroll
            for (int r = 0; r < 4; ++r)
                p[(rg * 16 + crow4 + r) * 64 + (cgb + q) * 16 + lrow] = acc[q][r];
    }
}

// ===== Kernel B: hxy-dots K=256 (bid<64) | dist-reduce (64..127) | sumS (128)
__global__ __launch_bounds__(256) void kB(const float* __restrict__ gF,
                                          const float* __restrict__ partials,
                                          const float* __restrict__ rsT,
                                          const float* __restrict__ hpartG,
                                          const float* __restrict__ x2,
                                          const float* __restrict__ w2,
                                          double* __restrict__ partials2,
                                          float* __restrict__ Sv,
                                          float* __restrict__ hxx,
                                          float* __restrict__ hyy,
                                          float* __restrict__ od) {
    __shared__ __align__(16) unsigned char smem[34816];
    const int bid = blockIdx.x;
    const int tid = threadIdx.x;
    if (bid < 64) {  // ---- fp32 dots over permuted G, K=256; double fold/chunk
        float (*la)[68] = (float(*)[68])smem;
        float (*lb)[68] = (float(*)[68])(smem + 17408);
        const int slc = (tid & 15) * 4;
        const int ry = tid >> 4, tx = tid & 15;
        double accd[4][4] = {};
        for (int c = 0; c < 4; ++c) {
            const int k0 = bid * 256 + c * 64;
            __syncthreads();
            for (int r = tid >> 4; r < 64; r += 16) {
                *(float4*)&la[r][slc] = *(const float4*)(gF + (size_t)r * SSn + k0 + slc);
                *(float4*)&lb[r][slc] = *(const float4*)(gF + (size_t)(64 + r) * SSn + k0 + slc);
            }
            __syncthreads();
            float acc[4][4] = {};
            for (int k = 0; k < 64; k += 4) {
                float4 av[4], bv[4];
#pragma unroll
                for (int i = 0; i < 4; ++i) av[i] = *(const float4*)&la[4 * ry + i][k];
#pragma unroll
                for (int j = 0; j < 4; ++j) bv[j] = *(const float4*)&lb[16 * j + tx][k];
#pragma unroll
                for (int i = 0; i < 4; ++i)
#pragma unroll
                    for (int j = 0; j < 4; ++j)
                        acc[i][j] += av[i].x * bv[j].x + av[i].y * bv[j].y +
                                     av[i].z * bv[j].z + av[i].w * bv[j].w;
            }
#pragma unroll
            for (int i = 0; i < 4; ++i)
#pragma unroll
                for (int j = 0; j < 4; ++j) accd[i][j] += (double)acc[i][j];
        }
        double* p = partials2 + (size_t)bid * 4096;
#pragma unroll
        for (int i = 0; i < 4; ++i)
#pragma unroll
            for (int j = 0; j < 4; ++j)
                p[(4 * ry + i) * 64 + 16 * j + tx] = accd[i][j];
    } else if (bid < 128) {  // ---- dist reduce (P=128) ----
        double* red = (double*)smem;
        const int b2 = bid - 64;
        const int o = tid & 63, sl = tid >> 6;
        const int i = b2 * 64 + o;
        double s = 0;
        for (int t = 0; t < 32; ++t)
            s += (double)partials[(size_t)(sl + 4 * t) * 4096 + i];
        red[sl * 64 + o] = s;
        __syncthreads();
        if (tid < 64) {
            double t = red[tid] + red[64 + tid] + red[128 + tid] + red[192 + tid];
            float d2 = x2[b2] + w2[tid] - 2.f * (float)t;
            od[b2 * 64 + tid] = sqrtf(fmaxf(d2, 0.f));
        }
    } else {  // ---- sumS: direct coalesced rsT reads; S, hxx, hyy ----
        if (tid < 128) {
            float s = 0.f, q = 0.f;
#pragma unroll 4
            for (int t = 0; t < 128; ++t) {
                float v = rsT[t * 128 + tid];
                s += v; q += v * v;
            }
            Sv[tid] = s;
            double val = (double)hpartG[tid] - (double)q * (1.0 / 64.0)
                       + (double)s * (double)s * (1.0 / 16384.0);
            if (tid < 64) hxx[tid] = (float)val; else hyy[tid - 64] = (float)val;
        }
    }
}

// ===== Kernel C: hxy reduce (P=64, doubles) + centering corr (64 x 256) ====
__global__ __launch_bounds__(256) void kC(const double* __restrict__ partials2,
                                          const float* __restrict__ rsT,
                                          const float* __restrict__ Sv,
                                          double* __restrict__ hxy) {
    __shared__ double red[256];
    const int b = blockIdx.x;
    const int o = threadIdx.x & 63;
    const int sl = threadIdx.x >> 6;
    const int i = b * 64 + o;
    double s = 0;
    for (int t = 0; t < 16; ++t)
        s += partials2[(size_t)(sl + 4 * t) * 4096 + i];
    double corr = 0;
    for (int t = 0; t < 32; ++t) {
        const int ss = sl * 32 + t;
        corr += (double)rsT[ss * 128 + b] * (double)rsT[ss * 128 + 64 + o];
    }
    red[sl * 64 + o] = s - corr * (1.0 / 64.0);
    __syncthreads();
    if (threadIdx.x < 64) {
        double t = red[threadIdx.x] + red[64 + threadIdx.x] +
                   red[128 + threadIdx.x] + red[192 + threadIdx.x];
        t += (double)Sv[b] * (double)Sv[64 + threadIdx.x] * (1.0 / 16384.0);
        hxy[b * 64 + threadIdx.x] = t;
    }
}

// ===== Kernel D: parallel argmin (== argmax of -log(r+eps), first-wins) ====
__global__ void finalize_k(const double* __restrict__ hxy, const float* __restrict__ hxx,
                           const float* __restrict__ hyy, float* __restrict__ out0,
                           float* __restrict__ oidx) {
    __shared__ double inv_sx[64], inv_sy[64];
    __shared__ double qv[256];
    __shared__ int qi[256];
    __shared__ int sidx[64];
    __shared__ double sred[4];
    const int tid = threadIdx.x;  // 256
    if (tid < 64) {
        inv_sx[tid] = 1.0 / sqrt((double)hxx[tid]);
        inv_sy[tid] = 1.0 / sqrt((double)hyy[tid]);
    }
    __syncthreads();
    {   // 4 threads per row b, 16 candidates each
        const int b = tid >> 2, q = tid & 3;
        double best = 1e300; int bi = 64;
        for (int c = q * 16; c < q * 16 + 16; ++c) {
            double v = fabs(hxy[b * 64 + c]) * inv_sy[c];
            if (v < best) { best = v; bi = c; }
        }
        qv[tid] = best; qi[tid] = bi;
    }
    __syncthreads();
    if (tid < 64) {
        double best = qv[4 * tid]; int bi = qi[4 * tid];
        for (int q = 1; q < 4; ++q) {
            if (qv[4 * tid + q] < best) { best = qv[4 * tid + q]; bi = qi[4 * tid + q]; }
        }
        sidx[tid] = bi;
        oidx[tid] = (float)bi;
    }
    __syncthreads();
    double s = 0.0;
    for (int e = tid; e < 4096; e += 256) {
        const int b = e >> 6, c = e & 63;
        const int ic = sidx[c];
        s += fabs(hxy[b * 64 + ic]) * inv_sx[b] * inv_sy[ic];
    }
#pragma unroll
    for (int o = 32; o > 0; o >>= 1) s += __shfl_down(s, o, 64);
    if ((tid & 63) == 0) sred[tid >> 6] = s;
    __syncthreads();
    if (tid == 0) {
        double t = sred[0] + sred[1] + sred[2] + sred[3];
        out0[0] = (float)(-log(t / 4096.0 + 1e-8));
    }
}

extern "C" void kernel_launch(void* const* d_in, const int* in_sizes, int n_in,
                              void* d_out, int out_size, void* d_ws, size_t ws_size,
                              hipStream_t stream) {
    const float* x = (const float*)d_in[0];   // (64, 65536)
    const float* w = (const float*)d_in[1];   // (64, 65536)
    float* out = (float*)d_out;
    // out: [0]=loss, [1..4096]=dist, [4097..4198400]=centroid copy, [4198401..]=idx
    float* ws = (float*)d_ws;
    float* gF        = ws;                        // 128*16384 fp32 (permuted grams)
    float* partials  = ws + 2097152;              // 128*4096 fp32 (dist)
    double* partials2 = (double*)(ws + 2621440);  // 64*4096 doubles (hxy)
    float* rsT       = ws + 3670016;              // 128*128 [s][mat]
    float* hpartG    = ws + 3686400;              // 128
    float* Sv        = ws + 3686528;              // 128
    float* x2        = ws + 3686656;              // 64
    float* w2        = ws + 3686720;              // 64
    float* hxx       = ws + 3686784;              // 64
    float* hyy       = ws + 3686848;              // 64
    double* hxyD     = (double*)(ws + 3686912);   // 4096 doubles (8B aligned)

    kA<<<256, 512, 0, stream>>>(x, w, gF, rsT, hpartG, x2, w2, partials, out + 4097);
    kB<<<129, 256, 0, stream>>>(gF, partials, rsT, hpartG, x2, w2,
                                partials2, Sv, hxx, hyy, out + 1);
    kC<<<64, 256, 0, stream>>>(partials2, rsT, Sv, hxyD);
    finalize_k<<<1, 256, 0, stream>>>(hxyD, hxx, hyy, out, out + 4198401);
}